// Round 4
// baseline (317.687 us; speedup 1.0000x reference)
//
#include <hip/hip_runtime.h>

// FNO2d "kinet" forward. BS=2, H=W=24, WIDTH=20, M1=M2=12, N=576, NPAIR=165600.
// All f32. Output (2,24,24,1) flat = 1152 floats.
//
// Collision algebra (verified round 2):
//   v_new[o] = v[o] + sum_q cmask[o,q] * [ (v[o]-v[q])/2 + vr[o,q]*R[c,q,o] ]
//   R[c,q,o] = +rv[pair(q,o)] if q<o else -rv[pair(o,q)].
//
// Round-4 change: rv state is never materialized. The recurrence
//   rv_k = normalize(rv_{k-1}*ori + ori + s_k),  ori = normalize(rv_init)
// depends only on rv_init and scalars, so k_vnew recomputes it on the fly
// for the ~11% of pairs that pass the collision mask. rv_init is transposed
// once to pair-major [b][pair][20] (80B rows) for single-line gathers.

#define N_     576
#define NPAIR_ 165600
#define C_     20

__device__ __forceinline__ float gelu_f(float x){
    return 0.5f * x * (1.0f + erff(x * 0.70710678118654752440f));
}

// ---------------- lift: concat(x, gx, gy) @ fc0_w + fc0_b -> (b,c,h,w) ----------------
__global__ void k_lift(const float* __restrict__ xin, const float* __restrict__ w,
                       const float* __restrict__ b, float* __restrict__ xo){
    int t = blockIdx.x*blockDim.x + threadIdx.x;   // t = bb*576 + hw
    if (t >= 2*N_) return;
    int hw = t % N_;
    int h = hw / 24, wc = hw % 24;
    float in[12];
    const float* xp = xin + (size_t)t*10;
    #pragma unroll
    for (int q=0;q<10;q++) in[q] = xp[q];
    in[10] = (float)h  * (1.0f/23.0f);
    in[11] = (float)wc * (1.0f/23.0f);
    #pragma unroll
    for (int c=0;c<C_;c++){
        float acc = b[c];
        #pragma unroll
        for (int q=0;q<12;q++) acc += in[q]*w[q*C_+c];
        xo[(size_t)(t/N_)*C_*N_ + (size_t)c*N_ + hw] = acc;
    }
}

// ------- one-time transpose: rv_init [b][c][pair] -> rvt [b][pair][20] -------
__global__ void k_tr(const float* __restrict__ rvi, float* __restrict__ rvt){
    int t = blockIdx.x*blockDim.x + threadIdx.x;   // b*NPAIR + pair
    if (t >= 2*NPAIR_) return;
    int bb = t / NPAIR_; int pr = t % NPAIR_;
    size_t ibase = (size_t)bb*C_*NPAIR_ + pr;
    float v[C_];
    #pragma unroll
    for (int c=0;c<C_;c++) v[c] = rvi[ibase + (size_t)c*NPAIR_];
    float4* dst = (float4*)(rvt + (size_t)t*C_);
    #pragma unroll
    for (int q=0;q<5;q++) dst[q] = make_float4(v[4*q],v[4*q+1],v[4*q+2],v[4*q+3]);
}

// ---------------- forward DFT: X[kx=0..23][ky=0..11] per (b,c) ----------------
__global__ void k_fft_fwd(const float* __restrict__ x, float* __restrict__ Xr, float* __restrict__ Xi){
    __shared__ float xt[576], Tr[288], Ti[288], cst[24], snt[24];
    int bc = blockIdx.x;           // b*20+c
    int tid = threadIdx.x;         // 288 threads
    if (tid < 24){
        float s, c;
        sincosf((float)tid * 0.26179938779914943654f, &s, &c);  // 2*pi/24
        cst[tid]=c; snt[tid]=s;
    }
    for (int q=tid;q<576;q+=288) xt[q] = x[(size_t)bc*576+q];
    __syncthreads();
    {   // stage 1: along w
        int h = tid/12, ky = tid%12;
        float ar=0.f, ai=0.f;
        for (int w=0;w<24;w++){
            int m = (ky*w) % 24;
            float v = xt[h*24+w];
            ar += v*cst[m];
            ai -= v*snt[m];
        }
        Tr[tid]=ar; Ti[tid]=ai;
    }
    __syncthreads();
    {   // stage 2: along h
        int kx = tid/12, ky = tid%12;
        float ar=0.f, ai=0.f;
        for (int h=0;h<24;h++){
            int m = (kx*h)%24;
            float tr=Tr[h*12+ky], ti=Ti[h*12+ky];
            float cc=cst[m], ss=snt[m];
            ar += tr*cc + ti*ss;
            ai += ti*cc - tr*ss;
        }
        Xr[(size_t)bc*288 + tid] = ar;
        Xi[(size_t)bc*288 + tid] = ai;
    }
}

// ------- fused mode-mix + inverse FFT; writes a_t pair-major [b][n][20] -------
__global__ void k_fft_inv(const float* __restrict__ Xr, const float* __restrict__ Xi,
                          const float* __restrict__ wr, const float* __restrict__ wi,
                          float* __restrict__ a_t){
    __shared__ float Fr[288], Fi[288], Yr[288], Yi[288], cst[24], snt[24];
    int bo = blockIdx.x; int bb = bo/20, o = bo%20;
    int tid = threadIdx.x;    // 576 threads
    if (tid < 24){
        float s, c;
        sincosf((float)tid * 0.26179938779914943654f, &s, &c);
        cst[tid]=c; snt[tid]=s;
    }
    if (tid < 288){   // mode mixing: F[kx][ky] = sum_i X[b,i,kx,ky]*W[i,o,...]
        int ky = tid%12, kx = tid/12;
        int half = (kx>=12) ? 1 : 0; int mx = kx - half*12;
        float ar=0.f, ai=0.f;
        for (int i=0;i<20;i++){
            float xr = Xr[(size_t)(bb*20+i)*288 + tid];
            float xi = Xi[(size_t)(bb*20+i)*288 + tid];
            size_t widx = ((((size_t)half*20+i)*20+o)*12+mx)*12+ky;
            float wrv = wr[widx], wiv = wi[widx];
            ar += xr*wrv - xi*wiv;
            ai += xr*wiv + xi*wrv;
        }
        Fr[tid]=ar; Fi[tid]=ai;
    }
    __syncthreads();
    if (tid < 288){  // Y[h][ky] = (1/24) sum_kx F[kx][ky] e^{+i 2pi kx h/24}
        int h = tid/12;
        float ar=0.f, ai=0.f;
        for (int kx=0;kx<24;kx++){
            int m=(kx*h)%24;
            float fr=Fr[kx*12 + (tid%12)], fi=Fi[kx*12 + (tid%12)];
            ar += fr*cst[m] - fi*snt[m];
            ai += fr*snt[m] + fi*cst[m];
        }
        Yr[tid]=ar*(1.0f/24.0f); Yi[tid]=ai*(1.0f/24.0f);
    }
    __syncthreads();
    {   // a[h][w] = (1/24)[ Re Y[h,0] + 2 sum_{ky=1..11} Re(Y[h,ky] e^{+i 2pi ky w/24}) ]
        int h = tid/24, w = tid%24;
        float acc = Yr[h*12+0];
        #pragma unroll
        for (int ky=1;ky<12;ky++){
            int m=(ky*w)%24;
            acc += 2.0f*(Yr[h*12+ky]*cst[m] - Yi[h*12+ky]*snt[m]);
        }
        a_t[((size_t)bb*N_ + tid)*C_ + o] = acc*(1.0f/24.0f);   // imag(ky=0) discarded by irfft
    }
}

// ------- p_t = einsum('bchw,oc->bohw', x, w_k)+w_b, pair-major [b][n][20] -------
__global__ void k_p(const float* __restrict__ x, const float* __restrict__ wk,
                    const float* __restrict__ wb, float* __restrict__ p_t){
    __shared__ float swk[400], swb[C_];
    int tid = threadIdx.x;                        // 64 threads
    for (int q=tid;q<400;q+=64) swk[q]=wk[q];
    if (tid < C_) swb[tid]=wb[tid];
    __syncthreads();
    int t = blockIdx.x*64 + tid;                  // (b,hw)
    if (t >= 2*N_) return;
    int bb = t / N_, hw = t % N_;
    float xi[C_];
    #pragma unroll
    for (int c=0;c<C_;c++) xi[c] = x[(size_t)(bb*C_+c)*N_+hw];
    float accv[C_];
    #pragma unroll
    for (int o=0;o<C_;o++){
        float acc = swb[o];
        #pragma unroll
        for (int c=0;c<C_;c++) acc += xi[c]*swk[o*C_+c];
        accv[o]=acc;
    }
    float4* dst = (float4*)(p_t + (size_t)t*C_);
    #pragma unroll
    for (int q=0;q<5;q++) dst[q] = make_float4(accv[4*q],accv[4*q+1],accv[4*q+2],accv[4*q+3]);
}

// ---------------- pairwise: v_r, u_x = exp(-x_r); atomic per-b max of v_r ----------------
__global__ void k_pair(const float* __restrict__ p_t, const float* __restrict__ a_t,
                       float* __restrict__ vr, float* __restrict__ ux, float* __restrict__ vmax){
    __shared__ float pi[C_], ai[C_], wred[9];
    int bb = blockIdx.x/N_, i = blockIdx.x%N_;
    int j = threadIdx.x;                         // 576 threads
    if (j < C_){ pi[j]=p_t[((size_t)bb*N_+i)*C_+j]; ai[j]=a_t[((size_t)bb*N_+i)*C_+j]; }
    __syncthreads();
    const float4* pj4 = (const float4*)(p_t + ((size_t)bb*N_+j)*C_);
    const float4* aj4 = (const float4*)(a_t + ((size_t)bb*N_+j)*C_);
    float ssx=0.f, ssv=0.f;
    #pragma unroll
    for (int q=0;q<5;q++){
        float4 pv = pj4[q], av = aj4[q];
        float dx, dv;
        dx = pi[4*q+0]-pv.x; dv = ai[4*q+0]-av.x; ssx += dx*dx; ssv += dv*dv;
        dx = pi[4*q+1]-pv.y; dv = ai[4*q+1]-av.y; ssx += dx*dx; ssv += dv*dv;
        dx = pi[4*q+2]-pv.z; dv = ai[4*q+2]-av.z; ssx += dx*dx; ssv += dv*dv;
        dx = pi[4*q+3]-pv.w; dv = ai[4*q+3]-av.w; ssx += dx*dx; ssv += dv*dv;
    }
    float xr  = sqrtf(ssx+1e-12f);
    float vrv = sqrtf(ssv+1e-12f);
    size_t idx = (size_t)(bb*N_+i)*N_ + j;
    ux[idx] = expf(-xr);
    vr[idx] = vrv;
    float m = vrv;
    #pragma unroll
    for (int off=32; off; off>>=1) m = fmaxf(m, __shfl_down(m, off, 64));
    if ((j&63)==0) wred[j>>6] = m;
    __syncthreads();
    if (j==0){
        float mm = wred[0];
        #pragma unroll
        for (int q=1;q<9;q++) mm = fmaxf(mm, wred[q]);
        atomicMax((unsigned int*)&vmax[bb], __float_as_uint(mm));   // v_r >= 0
    }
}

// -------- collision update; rv recomputed on the fly from transposed rv_init --------
// v_new[o] = v[o] + sum_q cmask[o,q]*[(v[o]-v[q])/2 + vr[o,q]*R[c,q,o]]
__global__ void k_vnew(const float* __restrict__ p_t, const float* __restrict__ a_t,
                       const float* __restrict__ vr, const float* __restrict__ ux,
                       const float* __restrict__ rvt, const float* __restrict__ vmax,
                       const float* __restrict__ rs, int klayer,
                       float* __restrict__ xout, int do_gelu){
    __shared__ short hlist[N_];
    int bb = blockIdx.x/N_, i = blockIdx.x%N_;   // i = output index o
    int lane = threadIdx.x;                      // 64 threads = 1 wave
    float vm = vmax[bb];
    const float thr = 0.1f;                      // f32(1.0 - 0.9) weak-typed in JAX
    const float* vrow = vr + (size_t)(bb*N_+i)*N_;
    const float* urow = ux + (size_t)(bb*N_+i)*N_;

    // phase 1: build compacted hit list (wave-uniform nhit)
    int nhit = 0;
    for (int base=0; base<N_; base+=64){
        int j = base + lane;
        float vrij = vrow[j];
        float m = (vrij/vm)*urow[j];
        bool hit = (m > thr) && (j != i);        // diagonal mathematically contributes 0
        unsigned long long bmask = __ballot(hit);
        int pos = __popcll(bmask & ((1ULL<<lane)-1ULL));
        if (hit) hlist[nhit + pos] = (short)j;
        nhit += (int)__popcll(bmask);
    }
    __syncthreads();

    float s_arr[4] = { rs[0], rs[1], rs[2], rs[3] };
    float sv[C_], rA[C_];
    #pragma unroll
    for (int c=0;c<C_;c++){ sv[c]=0.f; rA[c]=0.f; }

    // phase 2: hits distributed across lanes (~1 each)
    for (int t=lane; t<nhit; t+=64){
        int j = hlist[t];
        float vrij = vrow[j];
        float sgn = (j<i) ? 1.0f : -1.0f;        // R[c,j,i] sign
        int lo = (j<i)?j:i, hi = (j<i)?i:j;
        int pidx = lo*(2*N_-lo-1)/2 + (hi-lo-1);
        float vrs = sgn*vrij;
        // load rv_init row, recompute layer-k rv state
        float st[C_];
        {
            const float4* rp = (const float4*)(rvt + ((size_t)bb*NPAIR_ + pidx)*C_);
            #pragma unroll
            for (int q=0;q<5;q++){
                float4 rr = rp[q];
                st[4*q+0]=rr.x; st[4*q+1]=rr.y; st[4*q+2]=rr.z; st[4*q+3]=rr.w;
            }
        }
        float ssq = 0.f;
        #pragma unroll
        for (int c=0;c<C_;c++) ssq += st[c]*st[c];
        float ni = sqrtf(ssq);
        float orc[C_];
        #pragma unroll
        for (int c=0;c<C_;c++) orc[c] = st[c]/ni;
        for (int l=0; l<=klayer; l++){
            float s = s_arr[l];
            float nq = 0.f;
            #pragma unroll
            for (int c=0;c<C_;c++){
                float nv = st[c]*orc[c] + orc[c] + s;
                st[c] = nv; nq += nv*nv;
            }
            float nn = sqrtf(nq);
            #pragma unroll
            for (int c=0;c<C_;c++) st[c] /= nn;
        }
        const float4* ap = (const float4*)(a_t + ((size_t)bb*N_ + j)*C_);
        #pragma unroll
        for (int q=0;q<5;q++){
            float4 aa = ap[q];
            sv[4*q+0] += aa.x; rA[4*q+0] += vrs*st[4*q+0];
            sv[4*q+1] += aa.y; rA[4*q+1] += vrs*st[4*q+1];
            sv[4*q+2] += aa.z; rA[4*q+2] += vrs*st[4*q+2];
            sv[4*q+3] += aa.w; rA[4*q+3] += vrs*st[4*q+3];
        }
    }
    #pragma unroll
    for (int off=32; off; off>>=1){
        #pragma unroll
        for (int c=0;c<C_;c++){
            sv[c] += __shfl_xor(sv[c], off, 64);
            rA[c] += __shfl_xor(rA[c], off, 64);
        }
    }
    if (lane < C_){
        int c = lane;
        float cnt = (float)nhit;
        float vi = a_t[((size_t)bb*N_+i)*C_+c];
        float vnew = vi + 0.5f*(cnt*vi - sv[c]) + rA[c];
        float xn = p_t[((size_t)bb*N_+i)*C_+c] + vnew;
        if (do_gelu) xn = gelu_f(xn);
        xout[(size_t)(bb*C_+c)*N_+i] = xn;       // channel-major for fft/p/head
    }
}

// ---------------- head: gelu(x@fc1+b1)@fc2+b2, per position ----------------
__global__ void k_head(const float* __restrict__ x, const float* __restrict__ w1,
                       const float* __restrict__ b1, const float* __restrict__ w2,
                       const float* __restrict__ b2, float* __restrict__ out){
    __shared__ float xi[C_];
    __shared__ float part[2];
    int pos = blockIdx.x; int bb = pos/N_, hw = pos%N_;
    int t = threadIdx.x;                         // 128 threads
    if (t < C_) xi[t] = x[(size_t)(bb*C_+t)*N_+hw];
    __syncthreads();
    float h = b1[t];
    #pragma unroll
    for (int c=0;c<C_;c++) h += xi[c]*w1[c*128+t];
    float g = gelu_f(h) * w2[t];
    #pragma unroll
    for (int off=32; off; off>>=1) g += __shfl_down(g, off, 64);
    if ((t&63)==0) part[t>>6] = g;
    __syncthreads();
    if (t==0) out[pos] = part[0] + part[1] + b2[0];
}

extern "C" void kernel_launch(void* const* d_in, const int* in_sizes, int n_in,
                              void* d_out, int out_size, void* d_ws, size_t ws_size,
                              hipStream_t stream) {
    const float* in_x   = (const float*)d_in[0];
    // d_in[1] (v) is dead in the reference forward
    const float* fc0_w  = (const float*)d_in[2];
    const float* fc0_b  = (const float*)d_in[3];
    const float* sc_wr  = (const float*)d_in[4];
    const float* sc_wi  = (const float*)d_in[5];
    const float* w_k    = (const float*)d_in[6];
    const float* w_b    = (const float*)d_in[7];
    const float* fc1_w  = (const float*)d_in[8];
    const float* fc1_b  = (const float*)d_in[9];
    const float* fc2_w  = (const float*)d_in[10];
    const float* fc2_b  = (const float*)d_in[11];
    const float* rv_init= (const float*)d_in[12];
    const float* rv_s   = (const float*)d_in[13];
    float* out = (float*)d_out;
    float* ws  = (float*)d_ws;

    // workspace layout (floats); total 8,043,272 floats = 32.2 MB
    float* x_cur = ws;                 // 23040  [b][c][n]
    float* p_t   = ws + 23040;         // 23040  [b][n][20]
    float* a_t   = ws + 46080;         // 23040  [b][n][20]
    float* Xr    = ws + 69120;         // 11520
    float* Xi    = ws + 80640;         // 11520
    float* vr    = ws + 92160;         // 663552
    float* ux    = ws + 755712;        // 663552
    float* rvt   = ws + 1419264;       // 6624000  [b][pair][20] transposed rv_init
    float* vmax  = ws + 8043264;       // 8 = [4 layers][2 batches]

    hipMemsetAsync(vmax, 0, 8*sizeof(float), stream);

    k_lift<<<dim3((2*N_+63)/64), 64, 0, stream>>>(in_x, fc0_w, fc0_b, x_cur);
    k_tr<<<(2*NPAIR_+255)/256, 256, 0, stream>>>(rv_init, rvt);

    for (int k=0;k<4;k++){
        const size_t woff = (size_t)k*2*20*20*144;
        k_fft_fwd<<<40, 288, 0, stream>>>(x_cur, Xr, Xi);
        k_fft_inv<<<40, 576, 0, stream>>>(Xr, Xi, sc_wr+woff, sc_wi+woff, a_t);
        k_p<<<(2*N_+63)/64, 64, 0, stream>>>(x_cur, w_k + k*400, w_b + k*20, p_t);
        k_pair<<<2*N_, N_, 0, stream>>>(p_t, a_t, vr, ux, vmax + 2*k);
        k_vnew<<<2*N_, 64, 0, stream>>>(p_t, a_t, vr, ux, rvt, vmax + 2*k, rv_s, k, x_cur, (k<3) ? 1 : 0);
    }

    k_head<<<2*N_, 128, 0, stream>>>(x_cur, fc1_w, fc1_b, fc2_w, fc2_b, out);
}

// Round 5
// 310.098 us; speedup vs baseline: 1.0245x; 1.0245x over previous
//
#include <hip/hip_runtime.h>

// FNO2d "kinet" forward. BS=2, H=W=24, WIDTH=20, M1=M2=12, N=576, NPAIR=165600.
// All f32. Output (2,24,24,1) flat = 1152 floats.
//
// Collision algebra (verified round 2):
//   v_new[o] = v[o] + sum_q cmask[o,q] * [ (v[o]-v[q])/2 + vr[o,q]*R[c,q,o] ]
//   R[c,q,o] = +rv[pair(q,o)] if q<o else -rv[pair(o,q)].
//
// rv state is never materialized (round 4): recomputed on the fly per masked
// pair from pair-major rv_init. Round-5 fix: __launch_bounds__(64,1) on k_vnew
// — round 4's 56-VGPR cap spilled ~80 live floats to scratch (7.6 MB writes vs
// 92 KB actual output, 44 us/dispatch). Merged accumulator halves live regs.

#define N_     576
#define NPAIR_ 165600
#define C_     20

__device__ __forceinline__ float gelu_f(float x){
    return 0.5f * x * (1.0f + erff(x * 0.70710678118654752440f));
}

// ---------------- lift: concat(x, gx, gy) @ fc0_w + fc0_b -> (b,c,h,w) ----------------
__global__ void k_lift(const float* __restrict__ xin, const float* __restrict__ w,
                       const float* __restrict__ b, float* __restrict__ xo){
    int t = blockIdx.x*blockDim.x + threadIdx.x;   // t = bb*576 + hw
    if (t >= 2*N_) return;
    int hw = t % N_;
    int h = hw / 24, wc = hw % 24;
    float in[12];
    const float* xp = xin + (size_t)t*10;
    #pragma unroll
    for (int q=0;q<10;q++) in[q] = xp[q];
    in[10] = (float)h  * (1.0f/23.0f);
    in[11] = (float)wc * (1.0f/23.0f);
    #pragma unroll
    for (int c=0;c<C_;c++){
        float acc = b[c];
        #pragma unroll
        for (int q=0;q<12;q++) acc += in[q]*w[q*C_+c];
        xo[(size_t)(t/N_)*C_*N_ + (size_t)c*N_ + hw] = acc;
    }
}

// ------- one-time transpose: rv_init [b][c][pair] -> rvt [b][pair][20] -------
__global__ void k_tr(const float* __restrict__ rvi, float* __restrict__ rvt){
    int t = blockIdx.x*blockDim.x + threadIdx.x;   // b*NPAIR + pair
    if (t >= 2*NPAIR_) return;
    int bb = t / NPAIR_; int pr = t % NPAIR_;
    size_t ibase = (size_t)bb*C_*NPAIR_ + pr;
    float v[C_];
    #pragma unroll
    for (int c=0;c<C_;c++) v[c] = rvi[ibase + (size_t)c*NPAIR_];
    float4* dst = (float4*)(rvt + (size_t)t*C_);
    #pragma unroll
    for (int q=0;q<5;q++) dst[q] = make_float4(v[4*q],v[4*q+1],v[4*q+2],v[4*q+3]);
}

// ---------------- forward DFT: X[kx=0..23][ky=0..11] per (b,c) ----------------
__global__ void k_fft_fwd(const float* __restrict__ x, float* __restrict__ Xr, float* __restrict__ Xi){
    __shared__ float xt[576], Tr[288], Ti[288], cst[24], snt[24];
    int bc = blockIdx.x;           // b*20+c
    int tid = threadIdx.x;         // 288 threads
    if (tid < 24){
        float s, c;
        sincosf((float)tid * 0.26179938779914943654f, &s, &c);  // 2*pi/24
        cst[tid]=c; snt[tid]=s;
    }
    for (int q=tid;q<576;q+=288) xt[q] = x[(size_t)bc*576+q];
    __syncthreads();
    {   // stage 1: along w
        int h = tid/12, ky = tid%12;
        float ar=0.f, ai=0.f;
        for (int w=0;w<24;w++){
            int m = (ky*w) % 24;
            float v = xt[h*24+w];
            ar += v*cst[m];
            ai -= v*snt[m];
        }
        Tr[tid]=ar; Ti[tid]=ai;
    }
    __syncthreads();
    {   // stage 2: along h
        int kx = tid/12, ky = tid%12;
        float ar=0.f, ai=0.f;
        for (int h=0;h<24;h++){
            int m = (kx*h)%24;
            float tr=Tr[h*12+ky], ti=Ti[h*12+ky];
            float cc=cst[m], ss=snt[m];
            ar += tr*cc + ti*ss;
            ai += ti*cc - tr*ss;
        }
        Xr[(size_t)bc*288 + tid] = ar;
        Xi[(size_t)bc*288 + tid] = ai;
    }
}

// ------- fused mode-mix + inverse FFT; writes a_t pair-major [b][n][20] -------
__global__ void k_fft_inv(const float* __restrict__ Xr, const float* __restrict__ Xi,
                          const float* __restrict__ wr, const float* __restrict__ wi,
                          float* __restrict__ a_t){
    __shared__ float Fr[288], Fi[288], Yr[288], Yi[288], cst[24], snt[24];
    int bo = blockIdx.x; int bb = bo/20, o = bo%20;
    int tid = threadIdx.x;    // 576 threads
    if (tid < 24){
        float s, c;
        sincosf((float)tid * 0.26179938779914943654f, &s, &c);
        cst[tid]=c; snt[tid]=s;
    }
    if (tid < 288){   // mode mixing: F[kx][ky] = sum_i X[b,i,kx,ky]*W[i,o,...]
        int ky = tid%12, kx = tid/12;
        int half = (kx>=12) ? 1 : 0; int mx = kx - half*12;
        float ar=0.f, ai=0.f;
        for (int i=0;i<20;i++){
            float xr = Xr[(size_t)(bb*20+i)*288 + tid];
            float xi = Xi[(size_t)(bb*20+i)*288 + tid];
            size_t widx = ((((size_t)half*20+i)*20+o)*12+mx)*12+ky;
            float wrv = wr[widx], wiv = wi[widx];
            ar += xr*wrv - xi*wiv;
            ai += xr*wiv + xi*wrv;
        }
        Fr[tid]=ar; Fi[tid]=ai;
    }
    __syncthreads();
    if (tid < 288){  // Y[h][ky] = (1/24) sum_kx F[kx][ky] e^{+i 2pi kx h/24}
        int h = tid/12;
        float ar=0.f, ai=0.f;
        for (int kx=0;kx<24;kx++){
            int m=(kx*h)%24;
            float fr=Fr[kx*12 + (tid%12)], fi=Fi[kx*12 + (tid%12)];
            ar += fr*cst[m] - fi*snt[m];
            ai += fr*snt[m] + fi*cst[m];
        }
        Yr[tid]=ar*(1.0f/24.0f); Yi[tid]=ai*(1.0f/24.0f);
    }
    __syncthreads();
    {   // a[h][w] = (1/24)[ Re Y[h,0] + 2 sum_{ky=1..11} Re(Y[h,ky] e^{+i 2pi ky w/24}) ]
        int h = tid/24, w = tid%24;
        float acc = Yr[h*12+0];
        #pragma unroll
        for (int ky=1;ky<12;ky++){
            int m=(ky*w)%24;
            acc += 2.0f*(Yr[h*12+ky]*cst[m] - Yi[h*12+ky]*snt[m]);
        }
        a_t[((size_t)bb*N_ + tid)*C_ + o] = acc*(1.0f/24.0f);   // imag(ky=0) discarded by irfft
    }
}

// ------- p_t = einsum('bchw,oc->bohw', x, w_k)+w_b, pair-major [b][n][20] -------
__global__ void __launch_bounds__(64, 1)
k_p(const float* __restrict__ x, const float* __restrict__ wk,
    const float* __restrict__ wb, float* __restrict__ p_t){
    __shared__ float swk[400], swb[C_];
    int tid = threadIdx.x;                        // 64 threads
    for (int q=tid;q<400;q+=64) swk[q]=wk[q];
    if (tid < C_) swb[tid]=wb[tid];
    __syncthreads();
    int t = blockIdx.x*64 + tid;                  // (b,hw)
    if (t >= 2*N_) return;
    int bb = t / N_, hw = t % N_;
    float xi[C_];
    #pragma unroll
    for (int c=0;c<C_;c++) xi[c] = x[(size_t)(bb*C_+c)*N_+hw];
    float accv[C_];
    #pragma unroll
    for (int o=0;o<C_;o++){
        float acc = swb[o];
        #pragma unroll
        for (int c=0;c<C_;c++) acc += xi[c]*swk[o*C_+c];
        accv[o]=acc;
    }
    float4* dst = (float4*)(p_t + (size_t)t*C_);
    #pragma unroll
    for (int q=0;q<5;q++) dst[q] = make_float4(accv[4*q],accv[4*q+1],accv[4*q+2],accv[4*q+3]);
}

// ---------------- pairwise: v_r, u_x = exp(-x_r); atomic per-b max of v_r ----------------
__global__ void k_pair(const float* __restrict__ p_t, const float* __restrict__ a_t,
                       float* __restrict__ vr, float* __restrict__ ux, float* __restrict__ vmax){
    __shared__ float pi[C_], ai[C_], wred[9];
    int bb = blockIdx.x/N_, i = blockIdx.x%N_;
    int j = threadIdx.x;                         // 576 threads
    if (j < C_){ pi[j]=p_t[((size_t)bb*N_+i)*C_+j]; ai[j]=a_t[((size_t)bb*N_+i)*C_+j]; }
    __syncthreads();
    const float4* pj4 = (const float4*)(p_t + ((size_t)bb*N_+j)*C_);
    const float4* aj4 = (const float4*)(a_t + ((size_t)bb*N_+j)*C_);
    float ssx=0.f, ssv=0.f;
    #pragma unroll
    for (int q=0;q<5;q++){
        float4 pv = pj4[q], av = aj4[q];
        float dx, dv;
        dx = pi[4*q+0]-pv.x; dv = ai[4*q+0]-av.x; ssx += dx*dx; ssv += dv*dv;
        dx = pi[4*q+1]-pv.y; dv = ai[4*q+1]-av.y; ssx += dx*dx; ssv += dv*dv;
        dx = pi[4*q+2]-pv.z; dv = ai[4*q+2]-av.z; ssx += dx*dx; ssv += dv*dv;
        dx = pi[4*q+3]-pv.w; dv = ai[4*q+3]-av.w; ssx += dx*dx; ssv += dv*dv;
    }
    float xr  = sqrtf(ssx+1e-12f);
    float vrv = sqrtf(ssv+1e-12f);
    size_t idx = (size_t)(bb*N_+i)*N_ + j;
    ux[idx] = expf(-xr);
    vr[idx] = vrv;
    float m = vrv;
    #pragma unroll
    for (int off=32; off; off>>=1) m = fmaxf(m, __shfl_down(m, off, 64));
    if ((j&63)==0) wred[j>>6] = m;
    __syncthreads();
    if (j==0){
        float mm = wred[0];
        #pragma unroll
        for (int q=1;q<9;q++) mm = fmaxf(mm, wred[q]);
        atomicMax((unsigned int*)&vmax[bb], __float_as_uint(mm));   // v_r >= 0
    }
}

// -------- collision update; rv recomputed on the fly from transposed rv_init --------
// v_new[o] = v[o]*(1+cnt/2) + sum_q cmask[o,q]*[vr[o,q]*R[c,q,o] - v[q]/2]
__global__ void __launch_bounds__(64, 1)
k_vnew(const float* __restrict__ p_t, const float* __restrict__ a_t,
       const float* __restrict__ vr, const float* __restrict__ ux,
       const float* __restrict__ rvt, const float* __restrict__ vmax,
       const float* __restrict__ rs, int klayer,
       float* __restrict__ xout, int do_gelu){
    __shared__ short hlist[N_];
    int bb = blockIdx.x/N_, i = blockIdx.x%N_;   // i = output index o
    int lane = threadIdx.x;                      // 64 threads = 1 wave
    float vm = vmax[bb];
    const float thr = 0.1f;                      // f32(1.0 - 0.9) weak-typed in JAX
    const float* vrow = vr + (size_t)(bb*N_+i)*N_;
    const float* urow = ux + (size_t)(bb*N_+i)*N_;

    // phase 1: build compacted hit list (wave-uniform nhit)
    int nhit = 0;
    for (int base=0; base<N_; base+=64){
        int j = base + lane;
        float vrij = vrow[j];
        float m = (vrij/vm)*urow[j];
        bool hit = (m > thr) && (j != i);        // diagonal mathematically contributes 0
        unsigned long long bmask = __ballot(hit);
        int pos = __popcll(bmask & ((1ULL<<lane)-1ULL));
        if (hit) hlist[nhit + pos] = (short)j;
        nhit += (int)__popcll(bmask);
    }
    __syncthreads();

    float s_arr[4] = { rs[0], rs[1], rs[2], rs[3] };
    float macc[C_];                              // = rA[c] - 0.5*sv[c]
    #pragma unroll
    for (int c=0;c<C_;c++) macc[c]=0.f;

    // phase 2: hits distributed across lanes (~1 each)
    for (int t=lane; t<nhit; t+=64){
        int j = hlist[t];
        float vrij = vrow[j];
        float sgn = (j<i) ? 1.0f : -1.0f;        // R[c,j,i] sign
        int lo = (j<i)?j:i, hi = (j<i)?i:j;
        int pidx = lo*(2*N_-lo-1)/2 + (hi-lo-1);
        float vrs = sgn*vrij;
        // load rv_init row, recompute layer-k rv state
        float st[C_];
        {
            const float4* rp = (const float4*)(rvt + ((size_t)bb*NPAIR_ + pidx)*C_);
            #pragma unroll
            for (int q=0;q<5;q++){
                float4 rr = rp[q];
                st[4*q+0]=rr.x; st[4*q+1]=rr.y; st[4*q+2]=rr.z; st[4*q+3]=rr.w;
            }
        }
        float ssq = 0.f;
        #pragma unroll
        for (int c=0;c<C_;c++) ssq += st[c]*st[c];
        float ni = sqrtf(ssq);
        float orc[C_];
        #pragma unroll
        for (int c=0;c<C_;c++) orc[c] = st[c]/ni;
        for (int l=0; l<=klayer; l++){
            float s = s_arr[l];
            float nq = 0.f;
            #pragma unroll
            for (int c=0;c<C_;c++){
                float nv = st[c]*orc[c] + orc[c] + s;
                st[c] = nv; nq += nv*nv;
            }
            float nn = sqrtf(nq);
            #pragma unroll
            for (int c=0;c<C_;c++) st[c] /= nn;
        }
        const float4* ap = (const float4*)(a_t + ((size_t)bb*N_ + j)*C_);
        #pragma unroll
        for (int q=0;q<5;q++){
            float4 aa = ap[q];
            macc[4*q+0] += vrs*st[4*q+0] - 0.5f*aa.x;
            macc[4*q+1] += vrs*st[4*q+1] - 0.5f*aa.y;
            macc[4*q+2] += vrs*st[4*q+2] - 0.5f*aa.z;
            macc[4*q+3] += vrs*st[4*q+3] - 0.5f*aa.w;
        }
    }
    #pragma unroll
    for (int off=32; off; off>>=1){
        #pragma unroll
        for (int c=0;c<C_;c++) macc[c] += __shfl_xor(macc[c], off, 64);
    }
    if (lane < C_){
        int c = lane;
        float cnt = (float)nhit;
        float vi = a_t[((size_t)bb*N_+i)*C_+c];
        float vnew = vi + 0.5f*cnt*vi + macc[c];
        float xn = p_t[((size_t)bb*N_+i)*C_+c] + vnew;
        if (do_gelu) xn = gelu_f(xn);
        xout[(size_t)(bb*C_+c)*N_+i] = xn;       // channel-major for fft/p/head
    }
}

// ---------------- head: gelu(x@fc1+b1)@fc2+b2, per position ----------------
__global__ void k_head(const float* __restrict__ x, const float* __restrict__ w1,
                       const float* __restrict__ b1, const float* __restrict__ w2,
                       const float* __restrict__ b2, float* __restrict__ out){
    __shared__ float xi[C_];
    __shared__ float part[2];
    int pos = blockIdx.x; int bb = pos/N_, hw = pos%N_;
    int t = threadIdx.x;                         // 128 threads
    if (t < C_) xi[t] = x[(size_t)(bb*C_+t)*N_+hw];
    __syncthreads();
    float h = b1[t];
    #pragma unroll
    for (int c=0;c<C_;c++) h += xi[c]*w1[c*128+t];
    float g = gelu_f(h) * w2[t];
    #pragma unroll
    for (int off=32; off; off>>=1) g += __shfl_down(g, off, 64);
    if ((t&63)==0) part[t>>6] = g;
    __syncthreads();
    if (t==0) out[pos] = part[0] + part[1] + b2[0];
}

extern "C" void kernel_launch(void* const* d_in, const int* in_sizes, int n_in,
                              void* d_out, int out_size, void* d_ws, size_t ws_size,
                              hipStream_t stream) {
    const float* in_x   = (const float*)d_in[0];
    // d_in[1] (v) is dead in the reference forward
    const float* fc0_w  = (const float*)d_in[2];
    const float* fc0_b  = (const float*)d_in[3];
    const float* sc_wr  = (const float*)d_in[4];
    const float* sc_wi  = (const float*)d_in[5];
    const float* w_k    = (const float*)d_in[6];
    const float* w_b    = (const float*)d_in[7];
    const float* fc1_w  = (const float*)d_in[8];
    const float* fc1_b  = (const float*)d_in[9];
    const float* fc2_w  = (const float*)d_in[10];
    const float* fc2_b  = (const float*)d_in[11];
    const float* rv_init= (const float*)d_in[12];
    const float* rv_s   = (const float*)d_in[13];
    float* out = (float*)d_out;
    float* ws  = (float*)d_ws;

    // workspace layout (floats); total 8,043,272 floats = 32.2 MB
    float* x_cur = ws;                 // 23040  [b][c][n]
    float* p_t   = ws + 23040;         // 23040  [b][n][20]
    float* a_t   = ws + 46080;         // 23040  [b][n][20]
    float* Xr    = ws + 69120;         // 11520
    float* Xi    = ws + 80640;         // 11520
    float* vr    = ws + 92160;         // 663552
    float* ux    = ws + 755712;        // 663552
    float* rvt   = ws + 1419264;       // 6624000  [b][pair][20] transposed rv_init
    float* vmax  = ws + 8043264;       // 8 = [4 layers][2 batches]

    hipMemsetAsync(vmax, 0, 8*sizeof(float), stream);

    k_lift<<<dim3((2*N_+63)/64), 64, 0, stream>>>(in_x, fc0_w, fc0_b, x_cur);
    k_tr<<<(2*NPAIR_+255)/256, 256, 0, stream>>>(rv_init, rvt);

    for (int k=0;k<4;k++){
        const size_t woff = (size_t)k*2*20*20*144;
        k_fft_fwd<<<40, 288, 0, stream>>>(x_cur, Xr, Xi);
        k_fft_inv<<<40, 576, 0, stream>>>(Xr, Xi, sc_wr+woff, sc_wi+woff, a_t);
        k_p<<<(2*N_+63)/64, 64, 0, stream>>>(x_cur, w_k + k*400, w_b + k*20, p_t);
        k_pair<<<2*N_, N_, 0, stream>>>(p_t, a_t, vr, ux, vmax + 2*k);
        k_vnew<<<2*N_, 64, 0, stream>>>(p_t, a_t, vr, ux, rvt, vmax + 2*k, rv_s, k, x_cur, (k<3) ? 1 : 0);
    }

    k_head<<<2*N_, 128, 0, stream>>>(x_cur, fc1_w, fc1_b, fc2_w, fc2_b, out);
}

// Round 6
// 236.948 us; speedup vs baseline: 1.3407x; 1.3087x over previous
//
#include <hip/hip_runtime.h>

// FNO2d "kinet" forward. BS=2, H=W=24, WIDTH=20, M1=M2=12, N=576, NPAIR=165600.
// All f32. Output (2,24,24,1) flat = 1152 floats.
//
// Collision algebra (verified round 2):
//   v_new[o] = v[o] + sum_q cmask[o,q] * [ (v[o]-v[q])/2 + vr[o,q]*R[c,q,o] ]
//   R[c,q,o] = +rv[pair(q,o)] if q<o else -rv[pair(o,q)].
//
// rv state never materialized: recomputed per masked pair from pair-major
// rv_init. Round-6: k_vnew was latency-bound at 1 wave/block (occupancy 2.6%,
// VALUBusy 7.5%) -- now 256 threads/block (4 waves), deterministic two-pass
// hit compaction, cross-wave LDS reduction, rcp-mul instead of per-c divides.

#define N_     576
#define NPAIR_ 165600
#define C_     20

__device__ __forceinline__ float gelu_f(float x){
    return 0.5f * x * (1.0f + erff(x * 0.70710678118654752440f));
}

// ---------------- lift: concat(x, gx, gy) @ fc0_w + fc0_b -> (b,c,h,w) ----------------
__global__ void k_lift(const float* __restrict__ xin, const float* __restrict__ w,
                       const float* __restrict__ b, float* __restrict__ xo){
    int t = blockIdx.x*blockDim.x + threadIdx.x;   // t = bb*576 + hw
    if (t >= 2*N_) return;
    int hw = t % N_;
    int h = hw / 24, wc = hw % 24;
    float in[12];
    const float* xp = xin + (size_t)t*10;
    #pragma unroll
    for (int q=0;q<10;q++) in[q] = xp[q];
    in[10] = (float)h  * (1.0f/23.0f);
    in[11] = (float)wc * (1.0f/23.0f);
    #pragma unroll
    for (int c=0;c<C_;c++){
        float acc = b[c];
        #pragma unroll
        for (int q=0;q<12;q++) acc += in[q]*w[q*C_+c];
        xo[(size_t)(t/N_)*C_*N_ + (size_t)c*N_ + hw] = acc;
    }
}

// ------- one-time transpose: rv_init [b][c][pair] -> rvt [b][pair][20] -------
__global__ void k_tr(const float* __restrict__ rvi, float* __restrict__ rvt){
    int t = blockIdx.x*blockDim.x + threadIdx.x;   // b*NPAIR + pair
    if (t >= 2*NPAIR_) return;
    int bb = t / NPAIR_; int pr = t % NPAIR_;
    size_t ibase = (size_t)bb*C_*NPAIR_ + pr;
    float v[C_];
    #pragma unroll
    for (int c=0;c<C_;c++) v[c] = rvi[ibase + (size_t)c*NPAIR_];
    float4* dst = (float4*)(rvt + (size_t)t*C_);
    #pragma unroll
    for (int q=0;q<5;q++) dst[q] = make_float4(v[4*q],v[4*q+1],v[4*q+2],v[4*q+3]);
}

// ---------------- forward DFT: X[kx=0..23][ky=0..11] per (b,c) ----------------
__global__ void k_fft_fwd(const float* __restrict__ x, float* __restrict__ Xr, float* __restrict__ Xi){
    __shared__ float xt[576], Tr[288], Ti[288], cst[24], snt[24];
    int bc = blockIdx.x;           // b*20+c
    int tid = threadIdx.x;         // 288 threads
    if (tid < 24){
        float s, c;
        sincosf((float)tid * 0.26179938779914943654f, &s, &c);  // 2*pi/24
        cst[tid]=c; snt[tid]=s;
    }
    for (int q=tid;q<576;q+=288) xt[q] = x[(size_t)bc*576+q];
    __syncthreads();
    {   // stage 1: along w
        int h = tid/12, ky = tid%12;
        float ar=0.f, ai=0.f;
        for (int w=0;w<24;w++){
            int m = (ky*w) % 24;
            float v = xt[h*24+w];
            ar += v*cst[m];
            ai -= v*snt[m];
        }
        Tr[tid]=ar; Ti[tid]=ai;
    }
    __syncthreads();
    {   // stage 2: along h
        int kx = tid/12, ky = tid%12;
        float ar=0.f, ai=0.f;
        for (int h=0;h<24;h++){
            int m = (kx*h)%24;
            float tr=Tr[h*12+ky], ti=Ti[h*12+ky];
            float cc=cst[m], ss=snt[m];
            ar += tr*cc + ti*ss;
            ai += ti*cc - tr*ss;
        }
        Xr[(size_t)bc*288 + tid] = ar;
        Xi[(size_t)bc*288 + tid] = ai;
    }
}

// ------- fused mode-mix + inverse FFT; writes a_t pair-major [b][n][20] -------
__global__ void k_fft_inv(const float* __restrict__ Xr, const float* __restrict__ Xi,
                          const float* __restrict__ wr, const float* __restrict__ wi,
                          float* __restrict__ a_t){
    __shared__ float Fr[288], Fi[288], Yr[288], Yi[288], cst[24], snt[24];
    int bo = blockIdx.x; int bb = bo/20, o = bo%20;
    int tid = threadIdx.x;    // 576 threads
    if (tid < 24){
        float s, c;
        sincosf((float)tid * 0.26179938779914943654f, &s, &c);
        cst[tid]=c; snt[tid]=s;
    }
    if (tid < 288){   // mode mixing: F[kx][ky] = sum_i X[b,i,kx,ky]*W[i,o,...]
        int ky = tid%12, kx = tid/12;
        int half = (kx>=12) ? 1 : 0; int mx = kx - half*12;
        float ar=0.f, ai=0.f;
        for (int i=0;i<20;i++){
            float xr = Xr[(size_t)(bb*20+i)*288 + tid];
            float xi = Xi[(size_t)(bb*20+i)*288 + tid];
            size_t widx = ((((size_t)half*20+i)*20+o)*12+mx)*12+ky;
            float wrv = wr[widx], wiv = wi[widx];
            ar += xr*wrv - xi*wiv;
            ai += xr*wiv + xi*wrv;
        }
        Fr[tid]=ar; Fi[tid]=ai;
    }
    __syncthreads();
    if (tid < 288){  // Y[h][ky] = (1/24) sum_kx F[kx][ky] e^{+i 2pi kx h/24}
        int h = tid/12;
        float ar=0.f, ai=0.f;
        for (int kx=0;kx<24;kx++){
            int m=(kx*h)%24;
            float fr=Fr[kx*12 + (tid%12)], fi=Fi[kx*12 + (tid%12)];
            ar += fr*cst[m] - fi*snt[m];
            ai += fr*snt[m] + fi*cst[m];
        }
        Yr[tid]=ar*(1.0f/24.0f); Yi[tid]=ai*(1.0f/24.0f);
    }
    __syncthreads();
    {   // a[h][w] = (1/24)[ Re Y[h,0] + 2 sum_{ky=1..11} Re(Y[h,ky] e^{+i 2pi ky w/24}) ]
        int h = tid/24, w = tid%24;
        float acc = Yr[h*12+0];
        #pragma unroll
        for (int ky=1;ky<12;ky++){
            int m=(ky*w)%24;
            acc += 2.0f*(Yr[h*12+ky]*cst[m] - Yi[h*12+ky]*snt[m]);
        }
        a_t[((size_t)bb*N_ + tid)*C_ + o] = acc*(1.0f/24.0f);   // imag(ky=0) discarded by irfft
    }
}

// ------- p_t = einsum('bchw,oc->bohw', x, w_k)+w_b, pair-major [b][n][20] -------
__global__ void __launch_bounds__(64, 1)
k_p(const float* __restrict__ x, const float* __restrict__ wk,
    const float* __restrict__ wb, float* __restrict__ p_t){
    __shared__ float swk[400], swb[C_];
    int tid = threadIdx.x;                        // 64 threads
    for (int q=tid;q<400;q+=64) swk[q]=wk[q];
    if (tid < C_) swb[tid]=wb[tid];
    __syncthreads();
    int t = blockIdx.x*64 + tid;                  // (b,hw)
    if (t >= 2*N_) return;
    int bb = t / N_, hw = t % N_;
    float xi[C_];
    #pragma unroll
    for (int c=0;c<C_;c++) xi[c] = x[(size_t)(bb*C_+c)*N_+hw];
    float accv[C_];
    #pragma unroll
    for (int o=0;o<C_;o++){
        float acc = swb[o];
        #pragma unroll
        for (int c=0;c<C_;c++) acc += xi[c]*swk[o*C_+c];
        accv[o]=acc;
    }
    float4* dst = (float4*)(p_t + (size_t)t*C_);
    #pragma unroll
    for (int q=0;q<5;q++) dst[q] = make_float4(accv[4*q],accv[4*q+1],accv[4*q+2],accv[4*q+3]);
}

// ---------------- pairwise: v_r, u_x = exp(-x_r); atomic per-b max of v_r ----------------
__global__ void k_pair(const float* __restrict__ p_t, const float* __restrict__ a_t,
                       float* __restrict__ vr, float* __restrict__ ux, float* __restrict__ vmax){
    __shared__ float pi[C_], ai[C_], wred[9];
    int bb = blockIdx.x/N_, i = blockIdx.x%N_;
    int j = threadIdx.x;                         // 576 threads
    if (j < C_){ pi[j]=p_t[((size_t)bb*N_+i)*C_+j]; ai[j]=a_t[((size_t)bb*N_+i)*C_+j]; }
    __syncthreads();
    const float4* pj4 = (const float4*)(p_t + ((size_t)bb*N_+j)*C_);
    const float4* aj4 = (const float4*)(a_t + ((size_t)bb*N_+j)*C_);
    float ssx=0.f, ssv=0.f;
    #pragma unroll
    for (int q=0;q<5;q++){
        float4 pv = pj4[q], av = aj4[q];
        float dx, dv;
        dx = pi[4*q+0]-pv.x; dv = ai[4*q+0]-av.x; ssx += dx*dx; ssv += dv*dv;
        dx = pi[4*q+1]-pv.y; dv = ai[4*q+1]-av.y; ssx += dx*dx; ssv += dv*dv;
        dx = pi[4*q+2]-pv.z; dv = ai[4*q+2]-av.z; ssx += dx*dx; ssv += dv*dv;
        dx = pi[4*q+3]-pv.w; dv = ai[4*q+3]-av.w; ssx += dx*dx; ssv += dv*dv;
    }
    float xr  = sqrtf(ssx+1e-12f);
    float vrv = sqrtf(ssv+1e-12f);
    size_t idx = (size_t)(bb*N_+i)*N_ + j;
    ux[idx] = expf(-xr);
    vr[idx] = vrv;
    float m = vrv;
    #pragma unroll
    for (int off=32; off; off>>=1) m = fmaxf(m, __shfl_down(m, off, 64));
    if ((j&63)==0) wred[j>>6] = m;
    __syncthreads();
    if (j==0){
        float mm = wred[0];
        #pragma unroll
        for (int q=1;q<9;q++) mm = fmaxf(mm, wred[q]);
        atomicMax((unsigned int*)&vmax[bb], __float_as_uint(mm));   // v_r >= 0
    }
}

// -------- collision update; 256 threads (4 waves) per output row --------
// v_new[o] = v[o]*(1+cnt/2) + sum_q cmask[o,q]*[vr[o,q]*R[c,q,o] - v[q]/2]
__global__ void __launch_bounds__(256, 1)
k_vnew(const float* __restrict__ p_t, const float* __restrict__ a_t,
       const float* __restrict__ vr, const float* __restrict__ ux,
       const float* __restrict__ rvt, const float* __restrict__ vmax,
       const float* __restrict__ rs, int klayer,
       float* __restrict__ xout, int do_gelu){
    __shared__ short hlist[N_];
    __shared__ unsigned long long wmask[4][3];
    __shared__ int cnts[4];
    __shared__ float wacc[4][C_];
    int bb = blockIdx.x/N_, i = blockIdx.x%N_;   // i = output index o
    int tid = threadIdx.x;
    int wid = tid>>6, lane = tid&63;
    float vm = vmax[bb];
    const float thr = 0.1f;                      // f32(1.0 - 0.9) weak-typed in JAX
    const float* vrow = vr + (size_t)(bb*N_+i)*N_;
    const float* urow = ux + (size_t)(bb*N_+i)*N_;

    // pass 1: each wave tests j in [wid*144, wid*144+144)  (144 = 64+64+16)
    int jb = wid*144;
    unsigned long long m0, m1, m2;
    {
        int j = jb + lane;
        bool hit = ((vrow[j]/vm)*urow[j] > thr) && (j != i);
        m0 = __ballot(hit);
        j += 64;
        hit = ((vrow[j]/vm)*urow[j] > thr) && (j != i);
        m1 = __ballot(hit);
        j += 64;
        bool act = lane < 16;
        float vv = act ? vrow[j] : 0.f;
        float uu = act ? urow[j] : 0.f;
        hit = act && ((vv/vm)*uu > thr) && (j != i);
        m2 = __ballot(hit);
    }
    if (lane == 0){
        wmask[wid][0]=m0; wmask[wid][1]=m1; wmask[wid][2]=m2;
        cnts[wid] = (int)(__popcll(m0)+__popcll(m1)+__popcll(m2));
    }
    __syncthreads();
    int off = 0;
    #pragma unroll
    for (int w=0;w<4;w++) if (w < wid) off += cnts[w];
    int nhit = cnts[0]+cnts[1]+cnts[2]+cnts[3];
    // pass 2: deterministic compaction (wave order, bit order within wave)
    {
        unsigned long long below = (1ULL<<lane)-1ULL;
        int base = off;
        if (m0 & (1ULL<<lane)) hlist[base + __popcll(m0 & below)] = (short)(jb + lane);
        base += (int)__popcll(m0);
        if (m1 & (1ULL<<lane)) hlist[base + __popcll(m1 & below)] = (short)(jb + 64 + lane);
        base += (int)__popcll(m1);
        if (m2 & (1ULL<<lane)) hlist[base + __popcll(m2 & below)] = (short)(jb + 128 + lane);
    }
    __syncthreads();

    float s_arr[4] = { rs[0], rs[1], rs[2], rs[3] };
    float macc[C_];                              // = rA[c] - 0.5*sv[c]
    #pragma unroll
    for (int c=0;c<C_;c++) macc[c]=0.f;

    // phase 2: hits distributed over 256 lanes (~0-1 each)
    for (int t=tid; t<nhit; t+=256){
        int j = hlist[t];
        float vrij = vrow[j];
        float sgn = (j<i) ? 1.0f : -1.0f;        // R[c,j,i] sign
        int lo = (j<i)?j:i, hi = (j<i)?i:j;
        int pidx = lo*(2*N_-lo-1)/2 + (hi-lo-1);
        float vrs = sgn*vrij;
        float st[C_];
        {
            const float4* rp = (const float4*)(rvt + ((size_t)bb*NPAIR_ + pidx)*C_);
            #pragma unroll
            for (int q=0;q<5;q++){
                float4 rr = rp[q];
                st[4*q+0]=rr.x; st[4*q+1]=rr.y; st[4*q+2]=rr.z; st[4*q+3]=rr.w;
            }
        }
        float ssq = 0.f;
        #pragma unroll
        for (int c=0;c<C_;c++) ssq += st[c]*st[c];
        float ini = 1.0f/sqrtf(ssq);
        float orc[C_];
        #pragma unroll
        for (int c=0;c<C_;c++) orc[c] = st[c]*ini;
        for (int l=0; l<=klayer; l++){
            float s = s_arr[l];
            float nq = 0.f;
            #pragma unroll
            for (int c=0;c<C_;c++){
                float nv = st[c]*orc[c] + orc[c] + s;
                st[c] = nv; nq += nv*nv;
            }
            float inn = 1.0f/sqrtf(nq);
            #pragma unroll
            for (int c=0;c<C_;c++) st[c] *= inn;
        }
        const float4* ap = (const float4*)(a_t + ((size_t)bb*N_ + j)*C_);
        #pragma unroll
        for (int q=0;q<5;q++){
            float4 aa = ap[q];
            macc[4*q+0] += vrs*st[4*q+0] - 0.5f*aa.x;
            macc[4*q+1] += vrs*st[4*q+1] - 0.5f*aa.y;
            macc[4*q+2] += vrs*st[4*q+2] - 0.5f*aa.z;
            macc[4*q+3] += vrs*st[4*q+3] - 0.5f*aa.w;
        }
    }
    // wave-level reduce, then cross-wave via LDS
    #pragma unroll
    for (int off2=32; off2; off2>>=1){
        #pragma unroll
        for (int c=0;c<C_;c++) macc[c] += __shfl_xor(macc[c], off2, 64);
    }
    if (lane == 0){
        #pragma unroll
        for (int c=0;c<C_;c++) wacc[wid][c] = macc[c];
    }
    __syncthreads();
    if (tid < C_){
        int c = tid;
        float msum = wacc[0][c]+wacc[1][c]+wacc[2][c]+wacc[3][c];
        float cnt = (float)nhit;
        float vi = a_t[((size_t)bb*N_+i)*C_+c];
        float vnew = vi + 0.5f*cnt*vi + msum;
        float xn = p_t[((size_t)bb*N_+i)*C_+c] + vnew;
        if (do_gelu) xn = gelu_f(xn);
        xout[(size_t)(bb*C_+c)*N_+i] = xn;       // channel-major for fft/p/head
    }
}

// ---------------- head: gelu(x@fc1+b1)@fc2+b2, per position ----------------
__global__ void k_head(const float* __restrict__ x, const float* __restrict__ w1,
                       const float* __restrict__ b1, const float* __restrict__ w2,
                       const float* __restrict__ b2, float* __restrict__ out){
    __shared__ float xi[C_];
    __shared__ float part[2];
    int pos = blockIdx.x; int bb = pos/N_, hw = pos%N_;
    int t = threadIdx.x;                         // 128 threads
    if (t < C_) xi[t] = x[(size_t)(bb*C_+t)*N_+hw];
    __syncthreads();
    float h = b1[t];
    #pragma unroll
    for (int c=0;c<C_;c++) h += xi[c]*w1[c*128+t];
    float g = gelu_f(h) * w2[t];
    #pragma unroll
    for (int off=32; off; off>>=1) g += __shfl_down(g, off, 64);
    if ((t&63)==0) part[t>>6] = g;
    __syncthreads();
    if (t==0) out[pos] = part[0] + part[1] + b2[0];
}

extern "C" void kernel_launch(void* const* d_in, const int* in_sizes, int n_in,
                              void* d_out, int out_size, void* d_ws, size_t ws_size,
                              hipStream_t stream) {
    const float* in_x   = (const float*)d_in[0];
    // d_in[1] (v) is dead in the reference forward
    const float* fc0_w  = (const float*)d_in[2];
    const float* fc0_b  = (const float*)d_in[3];
    const float* sc_wr  = (const float*)d_in[4];
    const float* sc_wi  = (const float*)d_in[5];
    const float* w_k    = (const float*)d_in[6];
    const float* w_b    = (const float*)d_in[7];
    const float* fc1_w  = (const float*)d_in[8];
    const float* fc1_b  = (const float*)d_in[9];
    const float* fc2_w  = (const float*)d_in[10];
    const float* fc2_b  = (const float*)d_in[11];
    const float* rv_init= (const float*)d_in[12];
    const float* rv_s   = (const float*)d_in[13];
    float* out = (float*)d_out;
    float* ws  = (float*)d_ws;

    // workspace layout (floats); total 8,043,272 floats = 32.2 MB
    float* x_cur = ws;                 // 23040  [b][c][n]
    float* p_t   = ws + 23040;         // 23040  [b][n][20]
    float* a_t   = ws + 46080;         // 23040  [b][n][20]
    float* Xr    = ws + 69120;         // 11520
    float* Xi    = ws + 80640;         // 11520
    float* vr    = ws + 92160;         // 663552
    float* ux    = ws + 755712;        // 663552
    float* rvt   = ws + 1419264;       // 6624000  [b][pair][20] transposed rv_init
    float* vmax  = ws + 8043264;       // 8 = [4 layers][2 batches]

    hipMemsetAsync(vmax, 0, 8*sizeof(float), stream);

    k_lift<<<dim3((2*N_+63)/64), 64, 0, stream>>>(in_x, fc0_w, fc0_b, x_cur);
    k_tr<<<(2*NPAIR_+255)/256, 256, 0, stream>>>(rv_init, rvt);

    for (int k=0;k<4;k++){
        const size_t woff = (size_t)k*2*20*20*144;
        k_fft_fwd<<<40, 288, 0, stream>>>(x_cur, Xr, Xi);
        k_fft_inv<<<40, 576, 0, stream>>>(Xr, Xi, sc_wr+woff, sc_wi+woff, a_t);
        k_p<<<(2*N_+63)/64, 64, 0, stream>>>(x_cur, w_k + k*400, w_b + k*20, p_t);
        k_pair<<<2*N_, N_, 0, stream>>>(p_t, a_t, vr, ux, vmax + 2*k);
        k_vnew<<<2*N_, 256, 0, stream>>>(p_t, a_t, vr, ux, rvt, vmax + 2*k, rv_s, k, x_cur, (k<3) ? 1 : 0);
    }

    k_head<<<2*N_, 128, 0, stream>>>(x_cur, fc1_w, fc1_b, fc2_w, fc2_b, out);
}

// Round 7
// 228.801 us; speedup vs baseline: 1.3885x; 1.0356x over previous
//
#include <hip/hip_runtime.h>

// FNO2d "kinet" forward. BS=2, H=W=24, WIDTH=20, M1=M2=12, N=576, NPAIR=165600.
// All f32. Output (2,24,24,1) flat = 1152 floats.
//
// Collision algebra (verified round 2):
//   v_new[o] = v[o] + sum_q cmask[o,q] * [ (v[o]-v[q])/2 + vr[o,q]*R[c,q,o] ]
//   R[c,q,o] = +rv[pair(q,o)] if q<o else -rv[pair(o,q)].
//
// Round-7: dispatch-count reduction (23 -> 18) + kill vr/ux intermediates.
//  - v_r depends only on a  =>  k_pairmax reads a_t only, writes 1 atomicMax.
//  - k_vnew recomputes v_r/u_x on the fly (same ops, same order -> same bits).
//  - k_lift+k_tr fused (k_pre);  k_fft_fwd+k_p fused (k_specp, block roles).

#define N_     576
#define NPAIR_ 165600
#define C_     20
#define NB_TR  1294   // ceil(2*NPAIR/256)

__device__ __forceinline__ float gelu_f(float x){
    return 0.5f * x * (1.0f + erff(x * 0.70710678118654752440f));
}

// ---------- fused: rv_init transpose (blocks 0..NB_TR-1) + lift (last 5 blocks) ----------
__global__ void k_pre(const float* __restrict__ rvi, float* __restrict__ rvt,
                      const float* __restrict__ xin, const float* __restrict__ w,
                      const float* __restrict__ b, float* __restrict__ xo){
    int bid = blockIdx.x;
    if (bid < NB_TR){
        int t = bid*256 + threadIdx.x;             // b*NPAIR + pair
        if (t >= 2*NPAIR_) return;
        int bb = t / NPAIR_; int pr = t % NPAIR_;
        size_t ibase = (size_t)bb*C_*NPAIR_ + pr;
        float v[C_];
        #pragma unroll
        for (int c=0;c<C_;c++) v[c] = rvi[ibase + (size_t)c*NPAIR_];
        float4* dst = (float4*)(rvt + (size_t)t*C_);
        #pragma unroll
        for (int q=0;q<5;q++) dst[q] = make_float4(v[4*q],v[4*q+1],v[4*q+2],v[4*q+3]);
    } else {
        int t = (bid-NB_TR)*256 + threadIdx.x;     // bb*576 + hw
        if (t >= 2*N_) return;
        int hw = t % N_;
        int h = hw / 24, wc = hw % 24;
        float in[12];
        const float* xp = xin + (size_t)t*10;
        #pragma unroll
        for (int q=0;q<10;q++) in[q] = xp[q];
        in[10] = (float)h  * (1.0f/23.0f);
        in[11] = (float)wc * (1.0f/23.0f);
        #pragma unroll
        for (int c=0;c<C_;c++){
            float acc = b[c];
            #pragma unroll
            for (int q=0;q<12;q++) acc += in[q]*w[q*C_+c];
            xo[(size_t)(t/N_)*C_*N_ + (size_t)c*N_ + hw] = acc;
        }
    }
}

// ---- fused: forward DFT (blocks 0..39, per (b,c)) + p_t einsum (blocks 40..43) ----
__global__ void k_specp(const float* __restrict__ x, float* __restrict__ Xr, float* __restrict__ Xi,
                        const float* __restrict__ wk, const float* __restrict__ wb,
                        float* __restrict__ p_t){
    if (blockIdx.x < 40){
        __shared__ float xt[576], Tr[288], Ti[288], cst[24], snt[24];
        int bc = blockIdx.x;           // b*20+c
        int tid = threadIdx.x;         // 288 threads
        if (tid < 24){
            float s, c;
            sincosf((float)tid * 0.26179938779914943654f, &s, &c);  // 2*pi/24
            cst[tid]=c; snt[tid]=s;
        }
        for (int q=tid;q<576;q+=288) xt[q] = x[(size_t)bc*576+q];
        __syncthreads();
        {   // stage 1: along w
            int h = tid/12, ky = tid%12;
            float ar=0.f, ai=0.f;
            for (int w=0;w<24;w++){
                int m = (ky*w) % 24;
                float v = xt[h*24+w];
                ar += v*cst[m];
                ai -= v*snt[m];
            }
            Tr[tid]=ar; Ti[tid]=ai;
        }
        __syncthreads();
        {   // stage 2: along h
            int kx = tid/12, ky = tid%12;
            float ar=0.f, ai=0.f;
            for (int h=0;h<24;h++){
                int m = (kx*h)%24;
                float tr=Tr[h*12+ky], ti=Ti[h*12+ky];
                float cc=cst[m], ss=snt[m];
                ar += tr*cc + ti*ss;
                ai += ti*cc - tr*ss;
            }
            Xr[(size_t)bc*288 + tid] = ar;
            Xi[(size_t)bc*288 + tid] = ai;
        }
    } else {
        __shared__ float swk[400], swb[C_];
        int tid = threadIdx.x;                        // 288 threads
        for (int q=tid;q<400;q+=288) swk[q]=wk[q];
        if (tid < C_) swb[tid]=wb[tid];
        __syncthreads();
        int t = (blockIdx.x-40)*288 + tid;            // (b,hw) < 1152
        if (t >= 2*N_) return;
        int bb = t / N_, hw = t % N_;
        float xi[C_];
        #pragma unroll
        for (int c=0;c<C_;c++) xi[c] = x[(size_t)(bb*C_+c)*N_+hw];
        float accv[C_];
        #pragma unroll
        for (int o=0;o<C_;o++){
            float acc = swb[o];
            #pragma unroll
            for (int c=0;c<C_;c++) acc += xi[c]*swk[o*C_+c];
            accv[o]=acc;
        }
        float4* dst = (float4*)(p_t + (size_t)t*C_);
        #pragma unroll
        for (int q=0;q<5;q++) dst[q] = make_float4(accv[4*q],accv[4*q+1],accv[4*q+2],accv[4*q+3]);
    }
}

// ------- fused mode-mix + inverse FFT; writes a_t pair-major [b][n][20] -------
__global__ void k_fft_inv(const float* __restrict__ Xr, const float* __restrict__ Xi,
                          const float* __restrict__ wr, const float* __restrict__ wi,
                          float* __restrict__ a_t){
    __shared__ float Fr[288], Fi[288], Yr[288], Yi[288], cst[24], snt[24];
    int bo = blockIdx.x; int bb = bo/20, o = bo%20;
    int tid = threadIdx.x;    // 576 threads
    if (tid < 24){
        float s, c;
        sincosf((float)tid * 0.26179938779914943654f, &s, &c);
        cst[tid]=c; snt[tid]=s;
    }
    if (tid < 288){   // mode mixing: F[kx][ky] = sum_i X[b,i,kx,ky]*W[i,o,...]
        int ky = tid%12, kx = tid/12;
        int half = (kx>=12) ? 1 : 0; int mx = kx - half*12;
        float ar=0.f, ai=0.f;
        for (int i=0;i<20;i++){
            float xr = Xr[(size_t)(bb*20+i)*288 + tid];
            float xi = Xi[(size_t)(bb*20+i)*288 + tid];
            size_t widx = ((((size_t)half*20+i)*20+o)*12+mx)*12+ky;
            float wrv = wr[widx], wiv = wi[widx];
            ar += xr*wrv - xi*wiv;
            ai += xr*wiv + xi*wrv;
        }
        Fr[tid]=ar; Fi[tid]=ai;
    }
    __syncthreads();
    if (tid < 288){  // Y[h][ky] = (1/24) sum_kx F[kx][ky] e^{+i 2pi kx h/24}
        int h = tid/12;
        float ar=0.f, ai=0.f;
        for (int kx=0;kx<24;kx++){
            int m=(kx*h)%24;
            float fr=Fr[kx*12 + (tid%12)], fi=Fi[kx*12 + (tid%12)];
            ar += fr*cst[m] - fi*snt[m];
            ai += fr*snt[m] + fi*cst[m];
        }
        Yr[tid]=ar*(1.0f/24.0f); Yi[tid]=ai*(1.0f/24.0f);
    }
    __syncthreads();
    {   // a[h][w] = (1/24)[ Re Y[h,0] + 2 sum_{ky=1..11} Re(Y[h,ky] e^{+i 2pi ky w/24}) ]
        int h = tid/24, w = tid%24;
        float acc = Yr[h*12+0];
        #pragma unroll
        for (int ky=1;ky<12;ky++){
            int m=(ky*w)%24;
            acc += 2.0f*(Yr[h*12+ky]*cst[m] - Yi[h*12+ky]*snt[m]);
        }
        a_t[((size_t)bb*N_ + tid)*C_ + o] = acc*(1.0f/24.0f);   // imag(ky=0) discarded by irfft
    }
}

// ---------------- v_r global max (v_r depends only on a); no intermediates ----------------
__global__ void k_pairmax(const float* __restrict__ a_t, float* __restrict__ vmax){
    __shared__ float ai[C_], wred[9];
    int bb = blockIdx.x/N_, i = blockIdx.x%N_;
    int j = threadIdx.x;                         // 576 threads
    if (j < C_) ai[j]=a_t[((size_t)bb*N_+i)*C_+j];
    __syncthreads();
    const float4* aj4 = (const float4*)(a_t + ((size_t)bb*N_+j)*C_);
    float ssv=0.f;
    #pragma unroll
    for (int q=0;q<5;q++){
        float4 av = aj4[q];
        float dv;
        dv = ai[4*q+0]-av.x; ssv += dv*dv;
        dv = ai[4*q+1]-av.y; ssv += dv*dv;
        dv = ai[4*q+2]-av.z; ssv += dv*dv;
        dv = ai[4*q+3]-av.w; ssv += dv*dv;
    }
    float m = sqrtf(ssv+1e-12f);
    #pragma unroll
    for (int off=32; off; off>>=1) m = fmaxf(m, __shfl_down(m, off, 64));
    if ((j&63)==0) wred[j>>6] = m;
    __syncthreads();
    if (j==0){
        float mm = wred[0];
        #pragma unroll
        for (int q=1;q<9;q++) mm = fmaxf(mm, wred[q]);
        atomicMax((unsigned int*)&vmax[bb], __float_as_uint(mm));   // v_r >= 0
    }
}

// -------- collision update; v_r/u_x recomputed on the fly; 256 thr (4 waves)/row --------
// v_new[o] = v[o]*(1+cnt/2) + sum_q cmask[o,q]*[vr[o,q]*R[c,q,o] - v[q]/2]
__global__ void __launch_bounds__(256, 1)
k_vnew(const float* __restrict__ p_t, const float* __restrict__ a_t,
       const float* __restrict__ rvt, const float* __restrict__ vmax,
       const float* __restrict__ rs, int klayer,
       float* __restrict__ xout, int do_gelu){
    __shared__ float pi[C_], ai[C_];
    __shared__ short hlist[N_];
    __shared__ int cnts[4];
    __shared__ float wacc[4][C_];
    int bb = blockIdx.x/N_, i = blockIdx.x%N_;   // i = output index o
    int tid = threadIdx.x;
    int wid = tid>>6, lane = tid&63;
    if (tid < C_){ pi[tid]=p_t[((size_t)bb*N_+i)*C_+tid]; ai[tid]=a_t[((size_t)bb*N_+i)*C_+tid]; }
    __syncthreads();
    float vm = vmax[bb];
    const float thr = 0.1f;                      // f32(1.0 - 0.9) weak-typed in JAX
    const float4* pbase = (const float4*)(p_t + (size_t)bb*N_*C_);
    const float4* abase = (const float4*)(a_t + (size_t)bb*N_*C_);

    // pass 1: each wave tests j in [wid*144, wid*144+144)  (144 = 64+64+16)
    int jb = wid*144;
    unsigned long long m0, m1, m2;
    {
        auto test = [&](int j)->bool{
            const float4* pj = pbase + j*5;
            const float4* aj = abase + j*5;
            float ssx=0.f, ssv=0.f;
            #pragma unroll
            for (int q=0;q<5;q++){
                float4 pv = pj[q], av = aj[q];
                float dx, dv;
                dx = pi[4*q+0]-pv.x; dv = ai[4*q+0]-av.x; ssx += dx*dx; ssv += dv*dv;
                dx = pi[4*q+1]-pv.y; dv = ai[4*q+1]-av.y; ssx += dx*dx; ssv += dv*dv;
                dx = pi[4*q+2]-pv.z; dv = ai[4*q+2]-av.z; ssx += dx*dx; ssv += dv*dv;
                dx = pi[4*q+3]-pv.w; dv = ai[4*q+3]-av.w; ssx += dx*dx; ssv += dv*dv;
            }
            float vrv = sqrtf(ssv+1e-12f);
            float uxv = expf(-sqrtf(ssx+1e-12f));
            return ((vrv/vm)*uxv > thr) && (j != i);
        };
        int j = jb + lane;
        m0 = __ballot(test(j));
        m1 = __ballot(test(j+64));
        bool h2 = (lane<16) ? test(jb+128+lane) : false;
        m2 = __ballot(h2);
    }
    if (lane == 0) cnts[wid] = (int)(__popcll(m0)+__popcll(m1)+__popcll(m2));
    __syncthreads();
    int off = 0;
    #pragma unroll
    for (int w=0;w<4;w++) if (w < wid) off += cnts[w];
    int nhit = cnts[0]+cnts[1]+cnts[2]+cnts[3];
    // pass 2: deterministic compaction (wave order, bit order within wave)
    {
        unsigned long long below = (1ULL<<lane)-1ULL;
        int base = off;
        if (m0 & (1ULL<<lane)) hlist[base + __popcll(m0 & below)] = (short)(jb + lane);
        base += (int)__popcll(m0);
        if (m1 & (1ULL<<lane)) hlist[base + __popcll(m1 & below)] = (short)(jb + 64 + lane);
        base += (int)__popcll(m1);
        if (m2 & (1ULL<<lane)) hlist[base + __popcll(m2 & below)] = (short)(jb + 128 + lane);
    }
    __syncthreads();

    float s_arr[4] = { rs[0], rs[1], rs[2], rs[3] };
    float macc[C_];                              // = rA[c] - 0.5*sv[c]
    #pragma unroll
    for (int c=0;c<C_;c++) macc[c]=0.f;

    // phase 2: hits distributed over 256 lanes (~0-1 each)
    for (int t=tid; t<nhit; t+=256){
        int j = hlist[t];
        // recompute vrij and load a_j row (also needed for the sum)
        float av[C_];
        {
            const float4* aj = abase + j*5;
            #pragma unroll
            for (int q=0;q<5;q++){
                float4 aa = aj[q];
                av[4*q+0]=aa.x; av[4*q+1]=aa.y; av[4*q+2]=aa.z; av[4*q+3]=aa.w;
            }
        }
        float ssv=0.f;
        #pragma unroll
        for (int c=0;c<C_;c++){ float dv = ai[c]-av[c]; ssv += dv*dv; }
        float vrij = sqrtf(ssv+1e-12f);
        float sgn = (j<i) ? 1.0f : -1.0f;        // R[c,j,i] sign
        int lo = (j<i)?j:i, hi = (j<i)?i:j;
        int pidx = lo*(2*N_-lo-1)/2 + (hi-lo-1);
        float vrs = sgn*vrij;
        float st[C_];
        {
            const float4* rp = (const float4*)(rvt + ((size_t)bb*NPAIR_ + pidx)*C_);
            #pragma unroll
            for (int q=0;q<5;q++){
                float4 rr = rp[q];
                st[4*q+0]=rr.x; st[4*q+1]=rr.y; st[4*q+2]=rr.z; st[4*q+3]=rr.w;
            }
        }
        float ssq = 0.f;
        #pragma unroll
        for (int c=0;c<C_;c++) ssq += st[c]*st[c];
        float ini = 1.0f/sqrtf(ssq);
        float orc[C_];
        #pragma unroll
        for (int c=0;c<C_;c++) orc[c] = st[c]*ini;
        for (int l=0; l<=klayer; l++){
            float s = s_arr[l];
            float nq = 0.f;
            #pragma unroll
            for (int c=0;c<C_;c++){
                float nv = st[c]*orc[c] + orc[c] + s;
                st[c] = nv; nq += nv*nv;
            }
            float inn = 1.0f/sqrtf(nq);
            #pragma unroll
            for (int c=0;c<C_;c++) st[c] *= inn;
        }
        #pragma unroll
        for (int c=0;c<C_;c++) macc[c] += vrs*st[c] - 0.5f*av[c];
    }
    // wave-level reduce, then cross-wave via LDS
    #pragma unroll
    for (int off2=32; off2; off2>>=1){
        #pragma unroll
        for (int c=0;c<C_;c++) macc[c] += __shfl_xor(macc[c], off2, 64);
    }
    if (lane == 0){
        #pragma unroll
        for (int c=0;c<C_;c++) wacc[wid][c] = macc[c];
    }
    __syncthreads();
    if (tid < C_){
        int c = tid;
        float msum = wacc[0][c]+wacc[1][c]+wacc[2][c]+wacc[3][c];
        float cnt = (float)nhit;
        float vi = ai[c];
        float vnew = vi + 0.5f*cnt*vi + msum;
        float xn = pi[c] + vnew;
        if (do_gelu) xn = gelu_f(xn);
        xout[(size_t)(bb*C_+c)*N_+i] = xn;       // channel-major for fft/p/head
    }
}

// ---------------- head: gelu(x@fc1+b1)@fc2+b2, per position ----------------
__global__ void k_head(const float* __restrict__ x, const float* __restrict__ w1,
                       const float* __restrict__ b1, const float* __restrict__ w2,
                       const float* __restrict__ b2, float* __restrict__ out){
    __shared__ float xi[C_];
    __shared__ float part[2];
    int pos = blockIdx.x; int bb = pos/N_, hw = pos%N_;
    int t = threadIdx.x;                         // 128 threads
    if (t < C_) xi[t] = x[(size_t)(bb*C_+t)*N_+hw];
    __syncthreads();
    float h = b1[t];
    #pragma unroll
    for (int c=0;c<C_;c++) h += xi[c]*w1[c*128+t];
    float g = gelu_f(h) * w2[t];
    #pragma unroll
    for (int off=32; off; off>>=1) g += __shfl_down(g, off, 64);
    if ((t&63)==0) part[t>>6] = g;
    __syncthreads();
    if (t==0) out[pos] = part[0] + part[1] + b2[0];
}

extern "C" void kernel_launch(void* const* d_in, const int* in_sizes, int n_in,
                              void* d_out, int out_size, void* d_ws, size_t ws_size,
                              hipStream_t stream) {
    const float* in_x   = (const float*)d_in[0];
    // d_in[1] (v) is dead in the reference forward
    const float* fc0_w  = (const float*)d_in[2];
    const float* fc0_b  = (const float*)d_in[3];
    const float* sc_wr  = (const float*)d_in[4];
    const float* sc_wi  = (const float*)d_in[5];
    const float* w_k    = (const float*)d_in[6];
    const float* w_b    = (const float*)d_in[7];
    const float* fc1_w  = (const float*)d_in[8];
    const float* fc1_b  = (const float*)d_in[9];
    const float* fc2_w  = (const float*)d_in[10];
    const float* fc2_b  = (const float*)d_in[11];
    const float* rv_init= (const float*)d_in[12];
    const float* rv_s   = (const float*)d_in[13];
    float* out = (float*)d_out;
    float* ws  = (float*)d_ws;

    // workspace layout (floats); total 6,716,168 floats = 26.9 MB
    float* x_cur = ws;                 // 23040  [b][c][n]
    float* p_t   = ws + 23040;         // 23040  [b][n][20]
    float* a_t   = ws + 46080;         // 23040  [b][n][20]
    float* Xr    = ws + 69120;         // 11520
    float* Xi    = ws + 80640;         // 11520
    float* rvt   = ws + 92160;         // 6624000  [b][pair][20] transposed rv_init
    float* vmax  = ws + 6716160;       // 8 = [4 layers][2 batches]

    hipMemsetAsync(vmax, 0, 8*sizeof(float), stream);

    k_pre<<<NB_TR+5, 256, 0, stream>>>(rv_init, rvt, in_x, fc0_w, fc0_b, x_cur);

    for (int k=0;k<4;k++){
        const size_t woff = (size_t)k*2*20*20*144;
        k_specp<<<44, 288, 0, stream>>>(x_cur, Xr, Xi, w_k + k*400, w_b + k*20, p_t);
        k_fft_inv<<<40, 576, 0, stream>>>(Xr, Xi, sc_wr+woff, sc_wi+woff, a_t);
        k_pairmax<<<2*N_, N_, 0, stream>>>(a_t, vmax + 2*k);
        k_vnew<<<2*N_, 256, 0, stream>>>(p_t, a_t, rvt, vmax + 2*k, rv_s, k, x_cur, (k<3) ? 1 : 0);
    }

    k_head<<<2*N_, 128, 0, stream>>>(x_cur, fc1_w, fc1_b, fc2_w, fc2_b, out);
}